// Round 2
// baseline (73.933 us; speedup 1.0000x reference)
//
#include <hip/hip_runtime.h>

// QuanvLayer — closed form via Heisenberg picture.
//
// Circuit: RY(pi*x_q) encode; layer1 = [RX(p0), RY(p1), RZ(p2), H]; CNOT ring
// (0->1,1->2,2->3,3->0); final RY(p3..p6); measure <Z_q>.
//
// Final RY folded into measurement: out_q = cos(pf_q)<Z_q> - sin(pf_q)<X_q> (post-CNOT).
// CNOT ring conjugated backward (U = C30 C23 C12 C01; CNOT Pauli map is sign-free):
//   <Z0> -> Z1 Z2 Z3      <X0> -> X0 X1
//   <Z1> -> Z0 Z1         <X1> -> X1 X2
//   <Z2> -> Z0 Z1 Z2      <X2> -> X2 X3
//   <Z3> -> Z0 Z1 Z2 Z3   <X3> -> X3 X0 X1
// evaluated on the layer-1 PRODUCT state, so every term is a product of
// single-qubit Bloch components:
//   z0 = cos p0 * cos(pi x0)        x0 = sin(pi x0)          (RX preserves X)
//   z1 = cos(pi x1 + p1)            x1 = sin(pi x1 + p1)     (RY adds angles)
//   z2 = cos(pi x2)                 x2 = cos p2 * sin(pi x2) (RZ preserves Z)
//   z3 = sin(pi x3)                 x3 = cos(pi x3)          (H swaps X<->Z)
// Math identical to the 72 µs version (verified end-to-end there).
//
// v_sin_f32/v_cos_f32 take REVOLUTIONS: sin(pi*x) = v_sin(0.5*x), x in [0,1)
// -> in hardware range, zero range-reduction. Same for params (p in [0,pi)).
//
// This version: 4 patches/thread, block-contiguous (perfect per-instruction
// coalescing, i = blk*1024 + k*256 + tid; 1176*1024 == N exactly, no tail).
// Param trig (12 transcendentals, wave-uniform) hoisted out of the patch loop:
// 20 -> 11 transcendentals per patch. Nontemporal streaming loads/stores via
// native clang vector type (HIP_vector_type rejected by the builtin).

typedef float f32x4 __attribute__((ext_vector_type(4)));

__global__ __launch_bounds__(256) void quanv_kernel(
    const f32x4* __restrict__ x,    // [N] patches of 4 angles in [0,1)
    const float* __restrict__ prm,  // [7]
    f32x4* __restrict__ out,        // [N] <Z_q> outputs
    int n)
{
    const float INV_2PI = 0.15915494309189535f;  // rad -> revolutions

    // ---- wave-uniform param trig (native hw sin/cos; args < 0.5 rev)
    // Computed ONCE per thread, amortized over 4 patches.
    float A   = __builtin_amdgcn_cosf(prm[0] * INV_2PI);  // cos p0
    float Cp1 = __builtin_amdgcn_cosf(prm[1] * INV_2PI);
    float Sp1 = __builtin_amdgcn_sinf(prm[1] * INV_2PI);
    float Bc  = __builtin_amdgcn_cosf(prm[2] * INV_2PI);  // cos p2
    float Cf0 = __builtin_amdgcn_cosf(prm[3] * INV_2PI);
    float Sf0 = __builtin_amdgcn_sinf(prm[3] * INV_2PI);
    float Cf1 = __builtin_amdgcn_cosf(prm[4] * INV_2PI);
    float Sf1 = __builtin_amdgcn_sinf(prm[4] * INV_2PI);
    float Cf2 = __builtin_amdgcn_cosf(prm[5] * INV_2PI);
    float Sf2 = __builtin_amdgcn_sinf(prm[5] * INV_2PI);
    float Cf3 = __builtin_amdgcn_cosf(prm[6] * INV_2PI);
    float Sf3 = __builtin_amdgcn_sinf(prm[6] * INV_2PI);

    const int base = blockIdx.x * 1024 + threadIdx.x;

#pragma unroll
    for (int k = 0; k < 4; ++k) {
        const int i = base + k * 256;
        if (i >= n) break;

        const f32x4 xv = __builtin_nontemporal_load(&x[i]);

        // ---- full-angle trig of pi*x_q: rev = 0.5*x
        float c0 = __builtin_amdgcn_cosf(0.5f * xv.x);
        float s0 = __builtin_amdgcn_sinf(0.5f * xv.x);
        float c1 = __builtin_amdgcn_cosf(0.5f * xv.y);
        float s1 = __builtin_amdgcn_sinf(0.5f * xv.y);
        float c2 = __builtin_amdgcn_cosf(0.5f * xv.z);
        float s2 = __builtin_amdgcn_sinf(0.5f * xv.z);
        float c3 = __builtin_amdgcn_cosf(0.5f * xv.w);
        float s3 = __builtin_amdgcn_sinf(0.5f * xv.w);

        // ---- qubit-1 Bloch after RY(p1): angle addition
        float z1 = c1 * Cp1 - s1 * Sp1;   // cos(pi x1 + p1)
        float x1 = s1 * Cp1 + c1 * Sp1;   // sin(pi x1 + p1)

        // ---- shared products
        float P = A * c0 * z1;            // z0*z1
        float R = P * c2;                 // z0*z1*z2
        float Q = z1 * c2;                // z1*z2
        float T = s0 * x1;                // x0*x1
        float W = Bc * s2;                // x2

        f32x4 o;
        o.x = Cf0 * (Q * s3) - Sf0 * T;          // z1 z2 z3 | x0 x1
        o.y = Cf1 * P        - Sf1 * (x1 * W);   // z0 z1    | x1 x2
        o.z = Cf2 * R        - Sf2 * (W * c3);   // z0 z1 z2 | x2 x3
        o.w = Cf3 * (R * s3) - Sf3 * (c3 * T);   // z0..z3   | x3 x0 x1
        __builtin_nontemporal_store(o, &out[i]);
    }
}

extern "C" void kernel_launch(void* const* d_in, const int* in_sizes, int n_in,
                              void* d_out, int out_size, void* d_ws, size_t ws_size,
                              hipStream_t stream) {
    const f32x4* x  = (const f32x4*)d_in[0];    // [1204224, 4] f32
    const float* prm = (const float*)d_in[1];   // [7] f32
    f32x4* out = (f32x4*)d_out;                 // [1204224, 4] f32
    int n = in_sizes[0] / 4;
    int blocks = (n + 1023) / 1024;             // 1176 (exact: 1176*1024 == n)
    quanv_kernel<<<blocks, 256, 0, stream>>>(x, prm, out, n);
}